// Round 6
// baseline (154.655 us; speedup 1.0000x reference)
//
#include <hip/hip_runtime.h>
#include <hip/hip_fp16.h>
#include <math.h>

#define NB 128
#define NBINS 181
#define THRESH 90
#define SP 132        // spectrum row stride in half2 (132*4B = 528B per row)

__device__ __forceinline__ int br4(int i) {
    return ((i&1)<<3) | ((i&2)<<1) | ((i&4)>>1) | ((i&8)>>3);
}

// W16^e = exp(-2*pi*i*e/16), e = 0..7
__device__ const float TW16R[8] = { 1.f,  0.92387953f,  0.70710678f,  0.38268343f,
                                    0.f, -0.38268343f, -0.70710678f, -0.92387953f };
__device__ const float TW16I[8] = { 0.f, -0.38268343f, -0.70710678f, -0.92387953f,
                                   -1.f, -0.92387953f, -0.70710678f, -0.38268343f };
// W256^l, l = 0..15
__device__ const float W256R[16] = {
    1.00000000f, 0.99969882f, 0.99879546f, 0.99729046f, 0.99518473f, 0.99247953f,
    0.98917651f, 0.98527764f, 0.98078528f, 0.97570213f, 0.97003125f, 0.96377607f,
    0.95694034f, 0.94952818f, 0.94154407f, 0.93299280f };
__device__ const float W256I[16] = {
    -0.00000000f, -0.02454123f, -0.04906767f, -0.07356456f, -0.09801714f, -0.12241068f,
    -0.14673047f, -0.17096189f, -0.19509032f, -0.21910124f, -0.24298018f, -0.26671276f,
    -0.29028468f, -0.31368174f, -0.33688985f, -0.35989504f };

// 16-pt DIT FFT, input bit-reversed, output natural. All registers, all indices static.
__device__ __forceinline__ void fft16(float2 v[16]) {
    #pragma unroll
    for (int s = 0; s < 4; ++s) {
        const int half = 1 << s;
        #pragma unroll
        for (int gg = 0; gg < 16; gg += 2*half) {
            #pragma unroll
            for (int j = 0; j < half; ++j) {
                const float wr = TW16R[j << (3 - s)];
                const float wi = TW16I[j << (3 - s)];
                float2 a = v[gg + j], b = v[gg + j + half];
                float tr = b.x*wr - b.y*wi;
                float ti = b.x*wi + b.y*wr;
                v[gg + j]        = make_float2(a.x + tr, a.y + ti);
                v[gg + j + half] = make_float2(a.x - tr, a.y - ti);
            }
        }
    }
}

__device__ __forceinline__ void twiddle256(float2 v[16], int l) {
    const float c = W256R[l], s = W256I[l];
    float wr = c, wi = s;
    #pragma unroll
    for (int k = 1; k < 16; ++k) {
        float xr = v[k].x, xi = v[k].y;
        v[k] = make_float2(xr*wr - xi*wi, xr*wi + xi*wr);
        float nr = wr*c - wi*s;
        float ni = wr*s + wi*c;
        wr = nr; wi = ni;
    }
}

// One block per image. 1024 threads = 64 groups of 16 (one 256-pt FFT each).
__global__ __launch_bounds__(1024) void spectral_fused(const float* __restrict__ x,
                                                       const float* __restrict__ w,
                                                       const float* __restrict__ bias,
                                                       float* __restrict__ out) {
    __shared__ __half2 spec[256 * SP];   // 135168 B: half-spectrum + transpose scratch
    __shared__ float bins[192];
    __shared__ int   cnt[192];
    __shared__ float red[16];

    const int t = threadIdx.x;
    const int b = blockIdx.x;
    const int g = t >> 4, l = t & 15;
    const int lane = t & 63;

    if (t < 192) { bins[t] = 0.0f; cnt[t] = 0; }

    const float* xb = x + (size_t)b * 3 * 65536;

    // ---------------- row phase: packed row-pair FFTs, 2 passes ----------------
    #pragma unroll
    for (int pass = 0; pass < 2; ++pass) {
        const int p  = pass * 64 + g;        // pair 0..127
        const int r0 = 2 * p;
        const float* base0 = xb + r0 * 256;
        float2 v[16];
        #pragma unroll
        for (int i = 0; i < 16; ++i) {       // gray, direct global->reg (coalesced per 16 lanes)
            const int ci = 16 * br4(i) + l;
            float ra = base0[ci],       ga = base0[ci + 65536],       ba = base0[ci + 131072];
            float rb = base0[ci + 256], gb = base0[ci + 65536 + 256], bb = base0[ci + 131072 + 256];
            v[i] = make_float2(0.2989f*ra + 0.587f*ga + 0.114f*ba,
                               0.2989f*rb + 0.587f*gb + 0.114f*bb);
        }
        fft16(v);
        twiddle256(v, l);
        // rotation transpose through the pair's own spectrum rows (half scratch)
        #pragma unroll
        for (int k = 0; k < 16; ++k) {
            int s = k*16 + ((l + k) & 15);
            spec[(r0 + (s >> 7)) * SP + (s & 127)] = __float22half2_rn(v[k]);
        }
        #pragma unroll
        for (int i = 0; i < 16; ++i) {
            int s = l*16 + ((br4(i) + l) & 15);
            v[i] = __half22float2(spec[(r0 + (s >> 7)) * SP + (s & 127)]);
        }
        fft16(v);                            // thread l holds Z[l + 16*k2]
        // Hermitian unpack of packed pair (shuffle) + store k=0..128
        const int src = (lane & 48) | ((16 - l) & 15);
        #pragma unroll
        for (int k2 = 0; k2 < 8; ++k2) {
            float2 zm_s;
            zm_s.x = __shfl(v[15 - k2].x, src, 64);
            zm_s.y = __shfl(v[15 - k2].y, src, 64);
            float2 zm = (l == 0) ? v[(16 - k2) & 15] : zm_s;
            float2 z  = v[k2];
            int k = l + 16 * k2;
            spec[r0 * SP + k]       = __floats2half2_rn(0.5f*(z.x + zm.x), 0.5f*(z.y - zm.y));
            spec[(r0 + 1) * SP + k] = __floats2half2_rn(0.5f*(z.y + zm.y), 0.5f*(zm.x - z.x));
        }
        if (l == 0) {
            spec[r0 * SP + 128]       = __floats2half2_rn(v[8].x, 0.0f);
            spec[(r0 + 1) * SP + 128] = __floats2half2_rn(v[8].y, 0.0f);
        }
    }
    __syncthreads();

    // ---------------- col phase: cols 0..128, 3 passes, fused binning ----------------
    #pragma unroll
    for (int pass = 0; pass < 3; ++pass) {
        const int col = pass * 64 + g;
        if (col <= 128) {
            float2 v[16];
            #pragma unroll
            for (int i = 0; i < 16; ++i)
                v[i] = __half22float2(spec[(16 * br4(i) + l) * SP + col]);
            fft16(v);
            twiddle256(v, l);
            // rotation transpose within this column's own slots
            #pragma unroll
            for (int k = 0; k < 16; ++k) {
                int s = k*16 + ((l + k) & 15);
                spec[s * SP + col] = __float22half2_rn(v[k]);
            }
            #pragma unroll
            for (int i = 0; i < 16; ++i) {
                int s = l*16 + ((br4(i) + l) & 15);
                v[i] = __half22float2(spec[s * SP + col]);
            }
            fft16(v);                        // thread l holds X[u = l + 16*k2][col]
            const float dx  = (float)((col + 128) & 255) - 127.5f;
            const float dxm = (float)((384 - col) & 255) - 127.5f;
            const float dx2 = dx*dx, dxm2 = dxm*dxm;
            const bool mirror = (col >= 1) && (col <= 127);
            #pragma unroll
            for (int k2 = 0; k2 < 16; ++k2) {   // static index only (no scratch)
                int uu = l + 16 * k2;
                float re = v[k2].x, im = v[k2].y;
                float mag = 0.5f * __logf(re*re + im*im + 1e-16f);
                float dy = (float)((uu + 128) & 255) - 127.5f;
                atomicAdd(&bins[(int)sqrtf(dx2 + dy*dy)], mag);
                if (mirror) {
                    int um = (256 - uu) & 255;
                    float dy2 = (float)((um + 128) & 255) - 127.5f;
                    atomicAdd(&bins[(int)sqrtf(dxm2 + dy2*dy2)], mag);
                }
            }
        }
    }
    __syncthreads();

    // ---------------- profile: counts, normalize, dot ----------------
    {
        float dy = (float)(t & 255) - 127.5f;
        int x0 = (t >> 8) * 64;
        for (int xx = x0; xx < x0 + 64; ++xx) {
            float dxx = (float)xx - 127.5f;
            atomicAdd(&cnt[(int)sqrtf(dxx*dxx + dy*dy)], 1);
        }
    }
    __syncthreads();
    if (t < NBINS) bins[t] = bins[t] / (float)cnt[t];
    __syncthreads();

    float vv = (t < NBINS) ? bins[t] : bins[0];
    float mn = vv, mx = vv;
    #pragma unroll
    for (int m = 32; m >= 1; m >>= 1) {
        mn = fminf(mn, __shfl_xor(mn, m));
        mx = fmaxf(mx, __shfl_xor(mx, m));
    }
    if (lane == 0 && t < 192) { red[t >> 6] = mn; red[4 + (t >> 6)] = mx; }
    __syncthreads();
    if (t == 0) {
        red[8] = fminf(fminf(red[0], red[1]), red[2]);
        red[9] = fmaxf(fmaxf(red[4], red[5]), red[6]);
    }
    __syncthreads();
    const float mnv = red[8], mxv = red[9];

    float part = 0.0f;
    if (t < THRESH) {
        float f = (bins[(NBINS - THRESH) + t] - mnv) / (mxv - mnv);
        if (f != f) f = 0.0f;                // NaN -> 0
        part = f * w[t];
    }
    #pragma unroll
    for (int m = 32; m >= 1; m >>= 1) part += __shfl_xor(part, m);
    if (lane == 0 && t < 128) red[10 + (t >> 6)] = part;
    __syncthreads();
    if (t == 0) out[b] = red[10] + red[11] + bias[0];
}

extern "C" void kernel_launch(void* const* d_in, const int* in_sizes, int n_in,
                              void* d_out, int out_size, void* d_ws, size_t ws_size,
                              hipStream_t stream) {
    const float* x    = (const float*)d_in[0];  // (128,3,256,256)
    const float* w    = (const float*)d_in[1];  // (1,90)
    const float* bias = (const float*)d_in[2];  // (1,)
    float* out = (float*)d_out;                 // (128,1)
    spectral_fused<<<NB, 1024, 0, stream>>>(x, w, bias, out);
}

// Round 7
// 86.429 us; speedup vs baseline: 1.7894x; 1.7894x over previous
//
#include <hip/hip_runtime.h>
#include <hip/hip_fp16.h>
#include <math.h>

#define NB 128        // batch
#define N 256         // FFT size / image dim
#define NBINS 181
#define THRESH 90
#define RS 136        // row stride (float2) of intermediate F
#define GS 264        // row-kernel LDS group stride (float2)

__device__ __forceinline__ int br4(int i) {
    return ((i&1)<<3) | ((i&2)<<1) | ((i&4)>>1) | ((i&8)>>3);
}

// W16^e = exp(-2*pi*i*e/16), e = 0..7
__device__ const float TW16R[8] = { 1.f,  0.92387953f,  0.70710678f,  0.38268343f,
                                    0.f, -0.38268343f, -0.70710678f, -0.92387953f };
__device__ const float TW16I[8] = { 0.f, -0.38268343f, -0.70710678f, -0.92387953f,
                                   -1.f, -0.92387953f, -0.70710678f, -0.38268343f };
// W256^l, l = 0..15
__device__ const float W256R[16] = {
    1.00000000f, 0.99969882f, 0.99879546f, 0.99729046f, 0.99518473f, 0.99247953f,
    0.98917651f, 0.98527764f, 0.98078528f, 0.97570213f, 0.97003125f, 0.96377607f,
    0.95694034f, 0.94952818f, 0.94154407f, 0.93299280f };
__device__ const float W256I[16] = {
    -0.00000000f, -0.02454123f, -0.04906767f, -0.07356456f, -0.09801714f, -0.12241068f,
    -0.14673047f, -0.17096189f, -0.19509032f, -0.21910124f, -0.24298018f, -0.26671276f,
    -0.29028468f, -0.31368174f, -0.33688985f, -0.35989504f };

// 16-pt DIT FFT, input bit-reversed, output natural. All registers, static indices.
__device__ __forceinline__ void fft16(float2 v[16]) {
    #pragma unroll
    for (int s = 0; s < 4; ++s) {
        const int half = 1 << s;
        #pragma unroll
        for (int gg = 0; gg < 16; gg += 2*half) {
            #pragma unroll
            for (int j = 0; j < half; ++j) {
                const float wr = TW16R[j << (3 - s)];
                const float wi = TW16I[j << (3 - s)];
                float2 a = v[gg + j], b = v[gg + j + half];
                float tr = b.x*wr - b.y*wi;
                float ti = b.x*wi + b.y*wr;
                v[gg + j]        = make_float2(a.x + tr, a.y + ti);
                v[gg + j + half] = make_float2(a.x - tr, a.y - ti);
            }
        }
    }
}

__device__ __forceinline__ void twiddle256(float2 v[16], int l) {
    const float c = W256R[l], s = W256I[l];
    float wr = c, wi = s;
    #pragma unroll
    for (int k = 1; k < 16; ++k) {
        float xr = v[k].x, xi = v[k].y;
        v[k] = make_float2(xr*wr - xi*wi, xr*wi + xi*wr);
        float nr = wr*c - wi*s;
        float ni = wr*s + wi*c;
        wr = nr; wi = ni;
    }
}

// ---------------- Row pass (unchanged, proven clean): gray + packed-pair FFT ----------------
// grid (16, NB), 128 threads. Block = 8 row pairs; 16 threads per FFT.
__global__ __launch_bounds__(128) void row_fft_kernel(const float* __restrict__ x,
                                                      float2* __restrict__ F) {
    __shared__ float2 zbuf[8*GS];      // 16.9 KB

    const int t = threadIdx.x;
    const int b = blockIdx.y;
    const int pbase = blockIdx.x * 8;

    const int cidx = t & 63;
    const int sub  = t >> 6;           // 0..1
    const float* xb = x + (size_t)b * 3 * N * N;
    #pragma unroll
    for (int i = 0; i < 4; ++i) {
        int p  = i*2 + sub;
        int r0 = (pbase + p) * 2;
        const float* p0 = xb + (size_t)r0 * N + cidx*4;
        float4 a0 = *(const float4*)(p0);
        float4 a1 = *(const float4*)(p0 + N*N);
        float4 a2 = *(const float4*)(p0 + 2*N*N);
        float4 b0 = *(const float4*)(p0 + N);
        float4 b1 = *(const float4*)(p0 + N*N + N);
        float4 b2 = *(const float4*)(p0 + 2*N*N + N);
        float gx[4], gy[4];
        #pragma unroll
        for (int j = 0; j < 4; ++j) {
            gx[j] = 0.2989f*((&a0.x)[j]) + 0.587f*((&a1.x)[j]) + 0.114f*((&a2.x)[j]);
            gy[j] = 0.2989f*((&b0.x)[j]) + 0.587f*((&b1.x)[j]) + 0.114f*((&b2.x)[j]);
        }
        *(float4*)&zbuf[p*GS + cidx*4]     = make_float4(gx[0], gy[0], gx[1], gy[1]);
        *(float4*)&zbuf[p*GS + cidx*4 + 2] = make_float4(gx[2], gy[2], gx[3], gy[3]);
    }
    __syncthreads();

    const int g = t >> 4, l = t & 15;  // g 0..7
    float2 v[16];
    #pragma unroll
    for (int i = 0; i < 16; ++i) v[i] = zbuf[g*GS + 16*br4(i) + l];
    fft16(v);
    twiddle256(v, l);
    #pragma unroll
    for (int k = 0; k < 16; ++k) zbuf[g*GS + k*16 + ((l + k) & 15)] = v[k];
    #pragma unroll
    for (int i = 0; i < 16; ++i) v[i] = zbuf[g*GS + l*16 + ((br4(i) + l) & 15)];
    fft16(v);                           // thread l holds Z[l + 16*k2]

    const int lane = t & 63;
    const int src  = (lane & 48) | ((16 - l) & 15);
    float2* o0 = F + ((size_t)b * N + (size_t)(pbase + g) * 2) * RS;
    float2* o1 = o0 + RS;
    #pragma unroll
    for (int k2 = 0; k2 < 8; ++k2) {
        float2 zm_s;
        zm_s.x = __shfl(v[15 - k2].x, src, 64);
        zm_s.y = __shfl(v[15 - k2].y, src, 64);
        float2 zm = (l == 0) ? v[(16 - k2) & 15] : zm_s;
        float2 z  = v[k2];
        int k = l + 16*k2;
        o0[k] = make_float2(0.5f*(z.x + zm.x), 0.5f*(z.y - zm.y));
        o1[k] = make_float2(0.5f*(z.y + zm.y), 0.5f*(zm.x - z.x));
    }
    if (l == 0) {
        float2 z = v[8];                // k = 128, self-mirrored
        o0[128] = make_float2(z.x, 0.f);
        o1[128] = make_float2(z.y, 0.f);
    }
}

// ------------- Col pass: staged register FFT -> log|F| half spectrum (NO atomics) -------------
// grid (9, NB), 256 threads. 16 columns per block. Writes mag[b][xs][ys] (shifted coords).
__global__ __launch_bounds__(256) void col_fft_kernel(const float2* __restrict__ F,
                                                      __half* __restrict__ mag) {
    __shared__ float2 sbuf[16*272];    // 34816 B: staging (stride 17) + transpose regions
    __shared__ __half mag_lds[16*256]; // 8 KB

    const int t = threadIdx.x;
    const int b  = blockIdx.y;
    const int cg = blockIdx.x;         // 0..8

    // ---- stage: coalesced, stride-17 rows ----
    {
        const int c = t & 15, q = t >> 4;
        const int colr = cg*16 + c;
        const bool vread = (colr <= 128);
        const float2* base = F + (size_t)b * N * RS;
        #pragma unroll
        for (int i = 0; i < 16; ++i) {
            int row = i*16 + q;
            float2 vv = vread ? base[(size_t)row * RS + colr] : make_float2(0.f, 0.f);
            sbuf[row*17 + c] = vv;
        }
    }
    __syncthreads();

    const int g = t >> 4, l = t & 15;
    const int col = cg*16 + g;
    const bool valid = (col <= 128);
    float2 v[16];
    if (valid) {
        #pragma unroll
        for (int i = 0; i < 16; ++i) v[i] = sbuf[(16*br4(i) + l)*17 + g];
        fft16(v);
        twiddle256(v, l);
    }
    __syncthreads();                   // all stage reads done -> safe to overwrite sbuf

    if (valid) {
        // per-group 16x17 transpose region; same wave -> no barrier needed
        #pragma unroll
        for (int k = 0; k < 16; ++k) sbuf[g*272 + k*17 + l] = v[k];
        #pragma unroll
        for (int i = 0; i < 16; ++i) v[i] = sbuf[g*272 + l*17 + br4(i)];
        fft16(v);                      // thread l holds X[u = l + 16*k2][col]
        #pragma unroll
        for (int k2 = 0; k2 < 16; ++k2) {
            float re = v[k2].x, im = v[k2].y;
            float mg = 0.5f * __logf(re*re + im*im + 1e-16f);
            int ys = (l + 16*k2 + 128) & 255;      // fftshifted row coord
            mag_lds[g*256 + ys] = __float2half(mg);
        }
    }
    __syncthreads();

    // ---- coalesced store of this block's 16 shifted columns ----
    #pragma unroll
    for (int j = 0; j < 2; ++j) {
        int flat = t + 256*j;          // 512 float4 = 16 cols * 512 B
        int cl = flat >> 5, ch = flat & 31;
        if (cg < 8 || cl == 0) {
            int xs = (cg*16 + cl + 128) & 255;     // fftshifted col coord
            float4 d = *(const float4*)&mag_lds[cl*256 + ch*8];
            *(float4*)&mag[((size_t)b * 256 + xs) * 256 + ch*8] = d;
        }
    }
}

// ------------- Bin pass: gather-by-annulus, exact counts, NO atomics -------------
// grid (NBINS, NB), 64 threads (1 wave). prof[b][r] = mean of mag over annulus r.
__global__ __launch_bounds__(64) void bin_kernel(const __half* __restrict__ mag,
                                                 float* __restrict__ prof) {
    const int r = blockIdx.x, b = blockIdx.y;
    const int t = threadIdx.x;
    const __half* mb = mag + (size_t)b * 65536;

    float sum = 0.0f; int cn = 0;
    const float rr0 = (float)(r*r);
    const float rr1 = (float)((r+1)*(r+1));
    #pragma unroll
    for (int xi = 0; xi < 4; ++xi) {
        int xs = t + 64*xi;
        float dx = (float)xs - 127.5f;
        float dx2 = dx*dx;
        float hi2 = rr1 - dx2;
        if (hi2 <= 0.0f) continue;
        float lo2 = rr0 - dx2;
        int mlo = 0;
        if (lo2 > 0.0f) mlo = (int)ceilf(sqrtf(lo2) - 0.5f);   // boundary-safe: radius^2 has .5 frac
        int mhi = (int)ceilf(sqrtf(hi2) - 0.5f);
        if (mhi > 128) mhi = 128;
        if (mlo >= mhi) continue;
        // |dy| = m + 0.5, m in [mlo, mhi): rows ys = 128+m (lower half-plane) and 127-m
        if (xs == 0 || xs >= 128) {                 // stored column
            const __half* base = mb + xs*256;
            for (int m = mlo; m < mhi; ++m)
                sum += __half2float(base[128 + m]) + __half2float(base[127 - m]);
        } else {                                    // Hermitian mirror: col 256-xs, ys -> (256-ys)&255
            const __half* base = mb + (256 - xs)*256;
            for (int m = mlo; m < mhi; ++m)
                sum += __half2float(base[(128 - m) & 255]) + __half2float(base[(129 + m) & 255]);
        }
        cn += 2*(mhi - mlo);
    }
    #pragma unroll
    for (int msk = 32; msk >= 1; msk >>= 1) {
        sum += __shfl_xor(sum, msk);
        cn  += __shfl_xor(cn,  msk);
    }
    if (t == 0) prof[b*NBINS + r] = sum / (float)cn;
}

// ------------- Final: min/max normalize + dot with w -------------
__global__ __launch_bounds__(256) void final_kernel(const float* __restrict__ prof,
                                                    const float* __restrict__ w,
                                                    const float* __restrict__ bias,
                                                    float* __restrict__ out) {
    __shared__ float red[16];
    const int t = threadIdx.x, b = blockIdx.x;
    const int lane = t & 63, wv = t >> 6;

    float vv = (t < NBINS) ? prof[b*NBINS + t] : prof[b*NBINS];
    float mn = vv, mx = vv;
    #pragma unroll
    for (int m = 32; m >= 1; m >>= 1) {
        mn = fminf(mn, __shfl_xor(mn, m));
        mx = fmaxf(mx, __shfl_xor(mx, m));
    }
    if (lane == 0) { red[wv] = mn; red[4 + wv] = mx; }
    __syncthreads();
    if (t == 0) {
        red[8] = fminf(fminf(red[0], red[1]), fminf(red[2], red[3]));
        red[9] = fmaxf(fmaxf(red[4], red[5]), fmaxf(red[6], red[7]));
    }
    __syncthreads();
    const float mnv = red[8], mxv = red[9];

    float part = 0.0f;
    if (t < THRESH) {
        float f = (prof[b*NBINS + (NBINS - THRESH) + t] - mnv) / (mxv - mnv);
        if (f != f) f = 0.0f;          // NaN -> 0
        part = f * w[t];
    }
    #pragma unroll
    for (int m = 32; m >= 1; m >>= 1) part += __shfl_xor(part, m);
    if (lane == 0) red[10 + wv] = part;
    __syncthreads();
    if (t == 0) out[b] = red[10] + red[11] + red[12] + red[13] + bias[0];
}

extern "C" void kernel_launch(void* const* d_in, const int* in_sizes, int n_in,
                              void* d_out, int out_size, void* d_ws, size_t ws_size,
                              hipStream_t stream) {
    const float* x    = (const float*)d_in[0];  // (128,3,256,256)
    const float* w    = (const float*)d_in[1];  // (1,90)
    const float* bias = (const float*)d_in[2];  // (1,)
    float* out = (float*)d_out;                 // (128,1)

    char* ws = (char*)d_ws;
    float2* F    = (float2*)ws;                                   // 35,651,584 B
    __half* mag  = (__half*)(ws + (size_t)NB * N * RS * sizeof(float2));   // 16,777,216 B
    float*  prof = (float*)(ws + (size_t)NB * N * RS * sizeof(float2)
                               + (size_t)NB * 256 * 256 * sizeof(__half)); // 92,672 B

    row_fft_kernel<<<dim3(16, NB), 128, 0, stream>>>(x, F);
    col_fft_kernel<<<dim3(9, NB), 256, 0, stream>>>(F, mag);
    bin_kernel<<<dim3(NBINS, NB), 64, 0, stream>>>(mag, prof);
    final_kernel<<<NB, 256, 0, stream>>>(prof, w, bias, out);
}